// Round 6
// baseline (18752.832 us; speedup 1.0000x reference)
//
#include <hip/hip_runtime.h>

// RVQ encoder — bit-exact emulation of the harness numpy reference under the
// BLAS hypothesis: einsums evaluated via OpenBLAS sgemm (k-serial FMA chains,
// Q=384 panel splits), np.sum via scalar pairwise 8-accumulator blocks.
//  * E(d2) (K=128):   acc = fmaf(r[k], c[k], acc), k ascending, single chain
//  * x-proj (K=512):  (chain(0:384) + chain(384:512)) + in_b
//  * sem-bias(K=4096):((ch0+ch1)+...)+ch10 (10x384+256) + sem_b
//  * A,C:             numpy pairwise 8-acc, ((s0+s1)+(s2+s3))+((s4+s5)+(s6+s7))
//  * d2 = (A - 2f*E) + C ; argmin = first minimum (lowest index on ties)
//
// R6 = R5 with the code_norms_np pragma placement fixed (compile error: the
// '#pragma clang fp contract(off)' must open a compound statement).
//
// R5 change: eliminate the r[128] scratch spill STRUCTURALLY. Evidence
// (R0/R3/R4): allocator pins VGPR=128 and spills r[128] regardless of
// launch-bounds / waves_per_eu hints -> 5.6 GB scratch writeback + L1 thrash.
// New rvq_main: 32 rows/WG, lane-half d-split — lanes 0-31 hold r[0..63],
// lanes 32-63 hold r[64..127] of the SAME rows (rh[64] -> ~115 VGPR, fits
// the 128 bin with zero spill at 4 waves/SIMD). Exact numerics preserved via
// serial chain HANDOFF (half0 chain k=0..63, shfl accumulator, half1
// continues k=64..127 — bit-identical to one ascending chain); surrogate
// partials combined with one shfl_xor(32) per code (IEEE add commutative ->
// both halves identical shortlists). Same de-spill for xproj (a[64] chunks,
// panel split 6x64=384 preserved) and code_norms (streaming).
//
// ws: biasg f32[10240] | x f32[4194304] | norms f32[32768] | part f64[512]
// d_out (f32): quantized[4194304] | indices-as-f32[1048576] | closs[1]

// ---- np-exact helpers --------------------------------------------------------

__device__ __forceinline__ float np_add_scaled(float r, float b) {
#pragma clang fp contract(off)
  float t = 0.1f * b;
  return r + t;
}

__device__ __forceinline__ float np_ste(float x, float q) {
#pragma clang fp contract(off)
  float t = q - x;
  return x + t;
}

// ---- A: per-code norms (np pairwise 8-acc, streaming — no v[128] buffer) -----
__global__ __launch_bounds__(256) void code_norms_np(const float* __restrict__ cb,
                                                     float* __restrict__ norms) {
  int i = blockIdx.x * 256 + threadIdx.x;            // k*1024+c
  const float4* a = (const float4*)(cb + (size_t)i * 128);
  float result;
  {
#pragma clang fp contract(off)
    float4 u = a[0], v = a[1];                       // t=0: elements 0..7
    float s0 = u.x * u.x, s1 = u.y * u.y, s2 = u.z * u.z, s3 = u.w * u.w;
    float s4 = v.x * v.x, s5 = v.y * v.y, s6 = v.z * v.z, s7 = v.w * v.w;
#pragma unroll
    for (int t = 1; t < 16; ++t) {                   // elements 8t..8t+7
      u = a[2 * t]; v = a[2 * t + 1];
      s0 += u.x * u.x; s1 += u.y * u.y; s2 += u.z * u.z; s3 += u.w * u.w;
      s4 += v.x * v.x; s5 += v.y * v.y; s6 += v.z * v.z; s7 += v.w * v.w;
    }
    result = ((s0 + s1) + (s2 + s3)) + ((s4 + s5) + (s6 + s7));
  }
  norms[i] = result;
}

// ---- B: x = af @ in_w^T + in_b via sgemm semantics (K=512 -> 384+128) --------
// a[] reduced to 64-element chunks (8 chunks); accumulators carried across
// chunks keep the fmaf chain order identical. Panel boundary at chunk 6 (=384).
__global__ __launch_bounds__(256, 2) void xproj_blas(const float* __restrict__ af,
                                                     const float* __restrict__ in_w,
                                                     const float* __restrict__ in_b,
                                                     float* __restrict__ x) {
  int row = blockIdx.x * 256 + threadIdx.x;          // 0..32767
  const float* ar = af + (size_t)row * 512;
  for (int oc = 0; oc < 8; ++oc) {                   // 16 outputs per group
    float accA[16], accB[16];
#pragma unroll
    for (int o = 0; o < 16; ++o) { accA[o] = 0.f; accB[o] = 0.f; }
    for (int kc = 0; kc < 8; ++kc) {                 // 64-element k chunks
      float a[64];
      const float4* ap = (const float4*)(ar + kc * 64);
#pragma unroll
      for (int i = 0; i < 16; ++i) {
        float4 v = ap[i];
        a[4 * i] = v.x; a[4 * i + 1] = v.y; a[4 * i + 2] = v.z; a[4 * i + 3] = v.w;
      }
      if (kc < 6) {                                  // k = 0..383 -> panel A
#pragma unroll
        for (int o = 0; o < 16; ++o) {
          const float* wr = in_w + (size_t)(oc * 16 + o) * 512 + kc * 64;
          float acc = accA[o];
#pragma unroll
          for (int m = 0; m < 64; ++m) acc = fmaf(a[m], wr[m], acc);
          accA[o] = acc;
        }
      } else {                                       // k = 384..511 -> panel B
#pragma unroll
        for (int o = 0; o < 16; ++o) {
          const float* wr = in_w + (size_t)(oc * 16 + o) * 512 + kc * 64;
          float acc = accB[o];
#pragma unroll
          for (int m = 0; m < 64; ++m) acc = fmaf(a[m], wr[m], acc);
          accB[o] = acc;
        }
      }
    }
    {
#pragma clang fp contract(off)
#pragma unroll
      for (int o = 0; o < 16; ++o) {
        float E = accA[o] + accB[o];                 // panel junction add
        x[(size_t)row * 128 + oc * 16 + o] = E + in_b[oc * 16 + o];
      }
    }
  }
}

// ---- C: sem_bias via sgemm semantics (K=4096 -> 10x384 + 256 panels) ---------
__global__ __launch_bounds__(256) void sembias_blas(const float* __restrict__ sem_w,
                                                    const float* __restrict__ sem_b,
                                                    const float* __restrict__ ctx,
                                                    float* __restrict__ biasg) {
  int tid = blockIdx.x * 256 + threadIdx.x;          // 0..1279 = k*128+d
  if (tid >= 1280) return;
  int k = tid >> 7, d = tid & 127;
  const float* w = sem_w + (size_t)tid * 4096;
  float val[8];
  for (int j = 0; j < 11; ++j) {                     // sgemm k-panels
    int p0 = j * 384;
    int len = (j < 10) ? 384 : 256;                  // 10*384 + 256 = 4096
    float acc[8] = {0.f, 0.f, 0.f, 0.f, 0.f, 0.f, 0.f, 0.f};
    for (int i = 0; i < len; ++i) {
      float wv = w[p0 + i];
#pragma unroll
      for (int b = 0; b < 8; ++b)
        acc[b] = fmaf(wv, ctx[(size_t)b * 4096 + p0 + i], acc[b]);
    }
    {
#pragma clang fp contract(off)
      if (j == 0) {
#pragma unroll
        for (int b = 0; b < 8; ++b) val[b] = acc[b];
      } else {
#pragma unroll
        for (int b = 0; b < 8; ++b) val[b] = val[b] + acc[b];
      }
    }
  }
  {
#pragma clang fp contract(off)
#pragma unroll
    for (int b = 0; b < 8; ++b)
      biasg[((size_t)k * 8 + b) * 128 + d] = val[b] + sem_b[k * 128 + d];
  }
}

// ---- D: main 32-step loop — lane-half d-split, rh[64] register-resident ------
// WG = 512 threads = 8 waves; 32 rows/WG. Within a wave: lane 0-31 = rows,
// half h=0 (d 0..63); lane 32-63 = same rows, half h=1 (d 64..127).
// Wave w scans codes [w*128, (w+1)*128).
__global__ __launch_bounds__(512, 2) void rvq_main(const float* __restrict__ cb,
                                                   const float* __restrict__ norms,
                                                   const float* __restrict__ biasg,
                                                   const float* __restrict__ x,
                                                   float* __restrict__ outIdx) {
  const int lane = threadIdx.x & 63;
  const int wave = __builtin_amdgcn_readfirstlane(threadIdx.x >> 6);  // 0..7
  const int rl = lane & 31;                           // row within WG slab
  const int h = lane >> 5;                            // d-half: 0 or 1
  const int wg = blockIdx.x;                          // 0..1023
  const int row = (wg << 5) + rl;
  const int b = wg >> 7;                              // 128 WGs per batch row

  __shared__ float biasS[10 * 128];
  __shared__ float candV[8][32];
  __shared__ int candI[8][32];
  __shared__ int chosen[32];

  for (int t = threadIdx.x; t < 10 * 128; t += 512) {
    int kk = t >> 7, d = t & 127;
    biasS[t] = biasg[((size_t)kk * 8 + b) * 128 + d];
  }

  float rh[64];                                       // this lane's d-half
  {
    const float4* xp = (const float4*)(x + (size_t)row * 128 + (h << 6));
#pragma unroll
    for (int i = 0; i < 16; ++i) {
      float4 v = xp[i];
      rh[4 * i] = v.x; rh[4 * i + 1] = v.y; rh[4 * i + 2] = v.z; rh[4 * i + 3] = v.w;
    }
  }
  __syncthreads();

  const int c0 = wave << 7;                           // 128 codes per wave
  for (int k = 0; k < 32; ++k) {
    if (k < 10) {
#pragma unroll
      for (int d = 0; d < 64; ++d)
        rh[d] = np_add_scaled(rh[d], biasS[(k << 7) + (h << 6) + d]);
    }
    // ---- A = np pairwise 8-acc over full r, via half handoff --------------
    // numpy: s_j = r[j]^2; for t=1..15: s_j += r[8t+j]^2 ; combine pairwise.
    // t=0..7 live in half0, t=8..15 in half1. half0 computes its partial with
    // mul-init; half1 re-accumulates its terms serially ON TOP of the shuffled
    // partial (bit-identical to the single chain).
    float p[8];
    {
#pragma clang fp contract(off)
#pragma unroll
      for (int j = 0; j < 8; ++j) p[j] = rh[j] * rh[j];
#pragma unroll
      for (int t = 1; t < 8; ++t)
#pragma unroll
        for (int j = 0; j < 8; ++j) p[j] += rh[8 * t + j] * rh[8 * t + j];
    }
    float pin[8];
#pragma unroll
    for (int j = 0; j < 8; ++j) pin[j] = __shfl_xor(p[j], 32);
    float A = 0.f;
    if (h == 1) {
#pragma clang fp contract(off)
      float s[8];
#pragma unroll
      for (int j = 0; j < 8; ++j) s[j] = pin[j];
#pragma unroll
      for (int t = 0; t < 8; ++t)
#pragma unroll
        for (int j = 0; j < 8; ++j) s[j] += rh[8 * t + j] * rh[8 * t + j];
      A = ((s[0] + s[1]) + (s[2] + s[3])) + ((s[4] + s[5]) + (s[6] + s[7]));
    }

    const float* cbk = cb + ((size_t)k << 17);
    const float* nk = norms + (k << 10);
    // ---- surrogate scan: half-dot + shfl combine; per-wave top-4 ----------
    float b0 = 3.4e38f, b1 = 3.4e38f, b2 = 3.4e38f, b3 = 3.4e38f;
    int i0 = c0, i1 = c0, i2 = c0, i3 = c0;
    for (int c = c0; c < c0 + 128; ++c) {
      const float4* cp = (const float4*)(cbk + (c << 7) + (h << 6));
      float a0 = 0.f, a1 = 0.f, a2 = 0.f, a3 = 0.f;
#pragma unroll
      for (int i = 0; i < 16; ++i) {
        float4 v = cp[i];
        a0 = fmaf(rh[4 * i + 0], v.x, a0);
        a1 = fmaf(rh[4 * i + 1], v.y, a1);
        a2 = fmaf(rh[4 * i + 2], v.z, a2);
        a3 = fmaf(rh[4 * i + 3], v.w, a3);
      }
      float part = (a0 + a1) + (a2 + a3);
      float full = part + __shfl_xor(part, 32);       // add commutative: both
      float s = nk[c] - 2.0f * full;                  // halves identical
      bool lt0 = s < b0, lt1 = s < b1, lt2 = s < b2, lt3 = s < b3;
      b3 = lt2 ? b2 : (lt3 ? s : b3);  i3 = lt2 ? i2 : (lt3 ? c : i3);
      b2 = lt1 ? b1 : (lt2 ? s : b2);  i2 = lt1 ? i1 : (lt2 ? c : i2);
      b1 = lt0 ? b0 : (lt1 ? s : b1);  i1 = lt0 ? i0 : (lt1 ? c : i1);
      b0 = lt0 ? s : b0;               i0 = lt0 ? c : i0;
    }
    // ---- exact rescore: serial 128-chain via half handoff -----------------
    const float* p0c = cbk + ((size_t)i0 << 7) + (h << 6);
    const float* p1c = cbk + ((size_t)i1 << 7) + (h << 6);
    const float* p2c = cbk + ((size_t)i2 << 7) + (h << 6);
    const float* p3c = cbk + ((size_t)i3 << 7) + (h << 6);
    float E0 = 0.f, E1 = 0.f, E2 = 0.f, E3 = 0.f;     // half0: chain k=0..63
#pragma unroll
    for (int d = 0; d < 64; ++d) {
      float rd = rh[d];
      E0 = fmaf(rd, p0c[d], E0);
      E1 = fmaf(rd, p1c[d], E1);
      E2 = fmaf(rd, p2c[d], E2);
      E3 = fmaf(rd, p3c[d], E3);
    }
    float F0 = __shfl_xor(E0, 32), F1 = __shfl_xor(E1, 32);
    float F2 = __shfl_xor(E2, 32), F3 = __shfl_xor(E3, 32);
    if (h == 1) {                                     // continue chain k=64..127
      float G0 = F0, G1 = F1, G2 = F2, G3 = F3;
#pragma unroll
      for (int d = 0; d < 64; ++d) {
        float rd = rh[d];
        G0 = fmaf(rd, p0c[d], G0);
        G1 = fmaf(rd, p1c[d], G1);
        G2 = fmaf(rd, p2c[d], G2);
        G3 = fmaf(rd, p3c[d], G3);
      }
      float e0, e1, e2, e3;
      {
#pragma clang fp contract(off)
        float t0 = A - 2.0f * G0; e0 = t0 + nk[i0];
        float t1 = A - 2.0f * G1; e1 = t1 + nk[i1];
        float t2 = A - 2.0f * G2; e2 = t2 + nk[i2];
        float t3 = A - 2.0f * G3; e3 = t3 + nk[i3];
      }
      float bv = e0; int bi = i0;
      if (e1 < bv || (e1 == bv && i1 < bi)) { bv = e1; bi = i1; }
      if (e2 < bv || (e2 == bv && i2 < bi)) { bv = e2; bi = i2; }
      if (e3 < bv || (e3 == bv && i3 < bi)) { bv = e3; bi = i3; }
      candV[wave][rl] = bv;
      candI[wave][rl] = bi;
    }
    __syncthreads();
    if (wave == 0 && lane < 32) {
      float mv = candV[0][lane];
      int mi = candI[0][lane];
#pragma unroll
      for (int w = 1; w < 8; ++w) {
        float v = candV[w][lane];
        int ci = candI[w][lane];
        if (v < mv || (v == mv && ci < mi)) { mv = v; mi = ci; }
      }
      chosen[lane] = mi;
      outIdx[(k << 15) + row] = (float)mi;
    }
    __syncthreads();
    const float* q = cbk + ((size_t)chosen[rl] << 7) + (h << 6);
#pragma unroll
    for (int d = 0; d < 64; ++d) rh[d] = rh[d] - q[d];  // single sub, exact
  }
}

// ---- E: quantized (fp32 k-order accumulate + STE) + closs partials -----------
__global__ __launch_bounds__(256) void quant_closs(const float* __restrict__ cb,
                                                   const float* __restrict__ x,
                                                   const float* __restrict__ idxF,
                                                   float* __restrict__ outQ,
                                                   double* __restrict__ partials) {
  int gid = blockIdx.x * 256 + threadIdx.x;          // 0..131071
  int row = gid >> 2;
  int d0 = (gid & 3) << 5;
  const float* xr = x + (size_t)row * 128 + d0;
  float xv[32], qv[32];
#pragma unroll
  for (int i = 0; i < 32; ++i) { xv[i] = xr[i]; qv[i] = 0.f; }
  double cl = 0.0;
  for (int k = 0; k < 32; ++k) {
    int c = (int)idxF[(k << 15) + row];
    const float* qp = cb + ((size_t)k << 17) + ((size_t)c << 7) + d0;
#pragma unroll
    for (int i = 0; i < 32; ++i) {
      float v = qp[i];
      qv[i] = qv[i] + v;                  // fp32 adds in k-order (np order)
      float e = v - xv[i];
      cl += (double)e * (double)e;
    }
  }
  float* op = outQ + (size_t)row * 128 + d0;
#pragma unroll
  for (int i = 0; i < 32; ++i) op[i] = np_ste(xv[i], qv[i]);
  __shared__ double red[256];
  red[threadIdx.x] = cl;
  __syncthreads();
  for (int s = 128; s > 0; s >>= 1) {
    if (threadIdx.x < s) red[threadIdx.x] += red[threadIdx.x + s];
    __syncthreads();
  }
  if (threadIdx.x == 0) partials[blockIdx.x] = red[0];
}

// ---- F: final closs reduction ------------------------------------------------
__global__ __launch_bounds__(256) void closs_final(const double* __restrict__ partials,
                                                   float* __restrict__ out) {
  __shared__ double red[256];
  red[threadIdx.x] = partials[threadIdx.x] + partials[threadIdx.x + 256];
  __syncthreads();
  for (int s = 128; s > 0; s >>= 1) {
    if (threadIdx.x < s) red[threadIdx.x] += red[threadIdx.x + s];
    __syncthreads();
  }
  if (threadIdx.x == 0) out[0] = (float)(red[0] * (0.25 / 4194304.0));
}

extern "C" void kernel_launch(void* const* d_in, const int* in_sizes, int n_in,
                              void* d_out, int out_size, void* d_ws, size_t ws_size,
                              hipStream_t stream) {
  const float* af    = (const float*)d_in[0];
  const float* ctx   = (const float*)d_in[1];
  const float* in_w  = (const float*)d_in[2];
  const float* in_b  = (const float*)d_in[3];
  const float* cb    = (const float*)d_in[4];
  const float* sem_w = (const float*)d_in[5];
  const float* sem_b = (const float*)d_in[6];

  float* out     = (float*)d_out;
  float* outQ    = out;
  float* outIdx  = out + 4194304;
  float* outLoss = out + 5242880;

  float*  ws_bias  = (float*)d_ws;                    // 10240
  float*  ws_x     = ws_bias + 10240;                 // 4194304
  float*  ws_norms = ws_x + 4194304;                  // 32768
  double* ws_part  = (double*)(ws_norms + 32768);     // 512 doubles

  hipLaunchKernelGGL(code_norms_np, dim3(128), dim3(256), 0, stream, cb, ws_norms);
  hipLaunchKernelGGL(xproj_blas, dim3(128), dim3(256), 0, stream, af, in_w, in_b, ws_x);
  hipLaunchKernelGGL(sembias_blas, dim3(5), dim3(256), 0, stream, sem_w, sem_b, ctx,
                     ws_bias);
  hipLaunchKernelGGL(rvq_main, dim3(1024), dim3(512), 0, stream, cb, ws_norms,
                     ws_bias, ws_x, outIdx);
  hipLaunchKernelGGL(quant_closs, dim3(512), dim3(256), 0, stream, cb, ws_x,
                     outIdx, outQ, ws_part);
  hipLaunchKernelGGL(closs_final, dim3(1), dim3(256), 0, stream, ws_part, outLoss);
}

// Round 7
// 7087.218 us; speedup vs baseline: 2.6460x; 2.6460x over previous
//
#include <hip/hip_runtime.h>

// RVQ encoder — bit-exact emulation of the harness numpy reference under the
// BLAS hypothesis: einsums evaluated via OpenBLAS sgemm (k-serial FMA chains,
// Q=384 panel splits), np.sum via scalar pairwise 8-accumulator blocks.
//  * E(d2) (K=128):   acc = fmaf(r[k], c[k], acc), k ascending, single chain
//  * x-proj (K=512):  (chain(0:384) + chain(384:512)) + in_b
//  * sem-bias(K=4096):((ch0+ch1)+...)+ch10 (10x384+256) + sem_b
//  * A,C:             numpy pairwise 8-acc, ((s0+s1)+(s2+s3))+((s4+s5)+(s6+s7))
//  * d2 = (A - 2f*E) + C ; argmin = first minimum (lowest index on ties)
//
// R7 change: residual r moves to LDS; registers hold only accumulators.
// Occupancy law measured over R0-R6: resident waves/SIMD = 256/VGPR_Count
// (wave64 vreg = 2 physical SIMD32 regs) -> any r-in-VGPR design is pinned
// at 2 waves/SIMD (24%). New rvq_main: 512 thr / 8 waves, 64 rows, r in LDS
// [64][132] (pad 4 -> b128 reads hit the conflict-free 8-per-bank minimum).
// Wave w scans 128 codes in blocks of 8: per k4, one ds_read_b128 of own r4
// feeds 32 FMAs over 8 code accumulators. Codebook addresses are wave-uniform
// -> scalarizable. launch_bounds(512,4) pins the 64-VGPR bin = 4 waves/SIMD,
// whole grid co-resident. Numerics STRONGER: per-code acc is a single
// k-ascending fmaf chain == np_d2_blas E bit-exactly, so exact
// e=(A-2f*E)+C is computed inline for EVERY code (no surrogate/top-4/rescore).
// Running strict-< min keeps first-minimum ties; wave merge ascending.
//
// ws: biasg f32[10240] | x f32[4194304] | norms f32[32768] | part f64[512]
// d_out (f32): quantized[4194304] | indices-as-f32[1048576] | closs[1]

// ---- np-exact helpers --------------------------------------------------------

__device__ __forceinline__ float np_add_scaled(float r, float b) {
#pragma clang fp contract(off)
  float t = 0.1f * b;
  return r + t;
}

__device__ __forceinline__ float np_ste(float x, float q) {
#pragma clang fp contract(off)
  float t = q - x;
  return x + t;
}

// ---- A: per-code norms (np pairwise 8-acc, streaming) ------------------------
__global__ __launch_bounds__(256) void code_norms_np(const float* __restrict__ cb,
                                                     float* __restrict__ norms) {
  int i = blockIdx.x * 256 + threadIdx.x;            // k*1024+c
  const float4* a = (const float4*)(cb + (size_t)i * 128);
  float result;
  {
#pragma clang fp contract(off)
    float4 u = a[0], v = a[1];                       // t=0: elements 0..7
    float s0 = u.x * u.x, s1 = u.y * u.y, s2 = u.z * u.z, s3 = u.w * u.w;
    float s4 = v.x * v.x, s5 = v.y * v.y, s6 = v.z * v.z, s7 = v.w * v.w;
#pragma unroll
    for (int t = 1; t < 16; ++t) {                   // elements 8t..8t+7
      u = a[2 * t]; v = a[2 * t + 1];
      s0 += u.x * u.x; s1 += u.y * u.y; s2 += u.z * u.z; s3 += u.w * u.w;
      s4 += v.x * v.x; s5 += v.y * v.y; s6 += v.z * v.z; s7 += v.w * v.w;
    }
    result = ((s0 + s1) + (s2 + s3)) + ((s4 + s5) + (s6 + s7));
  }
  norms[i] = result;
}

// ---- B: x = af @ in_w^T + in_b via sgemm semantics (K=512 -> 384+128) --------
__global__ __launch_bounds__(256, 2) void xproj_blas(const float* __restrict__ af,
                                                     const float* __restrict__ in_w,
                                                     const float* __restrict__ in_b,
                                                     float* __restrict__ x) {
  int row = blockIdx.x * 256 + threadIdx.x;          // 0..32767
  const float* ar = af + (size_t)row * 512;
  for (int oc = 0; oc < 8; ++oc) {                   // 16 outputs per group
    float accA[16], accB[16];
#pragma unroll
    for (int o = 0; o < 16; ++o) { accA[o] = 0.f; accB[o] = 0.f; }
    for (int kc = 0; kc < 8; ++kc) {                 // 64-element k chunks
      float a[64];
      const float4* ap = (const float4*)(ar + kc * 64);
#pragma unroll
      for (int i = 0; i < 16; ++i) {
        float4 v = ap[i];
        a[4 * i] = v.x; a[4 * i + 1] = v.y; a[4 * i + 2] = v.z; a[4 * i + 3] = v.w;
      }
      if (kc < 6) {                                  // k = 0..383 -> panel A
#pragma unroll
        for (int o = 0; o < 16; ++o) {
          const float* wr = in_w + (size_t)(oc * 16 + o) * 512 + kc * 64;
          float acc = accA[o];
#pragma unroll
          for (int m = 0; m < 64; ++m) acc = fmaf(a[m], wr[m], acc);
          accA[o] = acc;
        }
      } else {                                       // k = 384..511 -> panel B
#pragma unroll
        for (int o = 0; o < 16; ++o) {
          const float* wr = in_w + (size_t)(oc * 16 + o) * 512 + kc * 64;
          float acc = accB[o];
#pragma unroll
          for (int m = 0; m < 64; ++m) acc = fmaf(a[m], wr[m], acc);
          accB[o] = acc;
        }
      }
    }
    {
#pragma clang fp contract(off)
#pragma unroll
      for (int o = 0; o < 16; ++o) {
        float E = accA[o] + accB[o];                 // panel junction add
        x[(size_t)row * 128 + oc * 16 + o] = E + in_b[oc * 16 + o];
      }
    }
  }
}

// ---- C: sem_bias via sgemm semantics (K=4096 -> 10x384 + 256 panels) ---------
__global__ __launch_bounds__(256) void sembias_blas(const float* __restrict__ sem_w,
                                                    const float* __restrict__ sem_b,
                                                    const float* __restrict__ ctx,
                                                    float* __restrict__ biasg) {
  int tid = blockIdx.x * 256 + threadIdx.x;          // 0..1279 = k*128+d
  if (tid >= 1280) return;
  int k = tid >> 7, d = tid & 127;
  const float* w = sem_w + (size_t)tid * 4096;
  float val[8];
  for (int j = 0; j < 11; ++j) {                     // sgemm k-panels
    int p0 = j * 384;
    int len = (j < 10) ? 384 : 256;                  // 10*384 + 256 = 4096
    float acc[8] = {0.f, 0.f, 0.f, 0.f, 0.f, 0.f, 0.f, 0.f};
    for (int i = 0; i < len; ++i) {
      float wv = w[p0 + i];
#pragma unroll
      for (int b = 0; b < 8; ++b)
        acc[b] = fmaf(wv, ctx[(size_t)b * 4096 + p0 + i], acc[b]);
    }
    {
#pragma clang fp contract(off)
      if (j == 0) {
#pragma unroll
        for (int b = 0; b < 8; ++b) val[b] = acc[b];
      } else {
#pragma unroll
        for (int b = 0; b < 8; ++b) val[b] = val[b] + acc[b];
      }
    }
  }
  {
#pragma clang fp contract(off)
#pragma unroll
    for (int b = 0; b < 8; ++b)
      biasg[((size_t)k * 8 + b) * 128 + d] = val[b] + sem_b[k * 128 + d];
  }
}

// ---- D: main 32-step loop — r in LDS, exact e for every code -----------------
// 512 threads = 8 waves; 64 rows/WG; lane = row. Wave w scans codes
// [w*128, w*128+128) in 16 blocks of 8 codes. Cooperative phases use the
// (row = tid&63, seg = tid>>6) partition: each thread owns 16 dims of one row.
#define RSTRIDE 132                                   // 128 + 4 pad (16B-aligned)
__global__ __launch_bounds__(512, 4) void rvq_main(const float* __restrict__ cb,
                                                   const float* __restrict__ norms,
                                                   const float* __restrict__ biasg,
                                                   const float* __restrict__ x,
                                                   float* __restrict__ outIdx) {
  const int tid = threadIdx.x;
  const int lane = tid & 63;
  const int wave = __builtin_amdgcn_readfirstlane(tid >> 6);  // 0..7
  const int wg = blockIdx.x;                          // 0..511
  const int row = (wg << 6) + lane;
  const int b = wg >> 6;

  __shared__ float rS[64 * RSTRIDE];                  // 33.8 KB
  __shared__ float biasS[10 * 128];
  __shared__ float candV[8][64];
  __shared__ int candI[8][64];
  __shared__ int chosen[64];

  for (int t = tid; t < 10 * 128; t += 512) {
    biasS[t] = biasg[((size_t)(t >> 7) * 8 + b) * 128 + (t & 127)];
  }
  {
    const int r0 = tid & 63, seg = tid >> 6;          // 16 dims per thread
    const float4* xp = (const float4*)(x + (size_t)((wg << 6) + r0) * 128 + seg * 16);
    float4* rp = (float4*)(rS + r0 * RSTRIDE + seg * 16);
#pragma unroll
    for (int i = 0; i < 4; ++i) rp[i] = xp[i];
  }
  __syncthreads();

  const int c0 = wave << 7;                           // 128 codes per wave
  const float* rrow = rS + lane * RSTRIDE;
  const float4* r4p = (const float4*)rrow;

  for (int k = 0; k < 32; ++k) {
    if (k < 10) {                                     // bias add, np order
      const int r0 = tid & 63, seg = tid >> 6;
      float* rp = rS + r0 * RSTRIDE + seg * 16;
      const float* bp = biasS + (k << 7) + seg * 16;
#pragma unroll
      for (int d = 0; d < 16; ++d) rp[d] = np_add_scaled(rp[d], bp[d]);
      __syncthreads();
    }
    // A = np pairwise 8-acc over own row (redundant per wave; read-only)
    float A;
    {
#pragma clang fp contract(off)
      float4 u = r4p[0], v = r4p[1];
      float s0 = u.x * u.x, s1 = u.y * u.y, s2 = u.z * u.z, s3 = u.w * u.w;
      float s4 = v.x * v.x, s5 = v.y * v.y, s6 = v.z * v.z, s7 = v.w * v.w;
#pragma unroll
      for (int t = 1; t < 16; ++t) {
        u = r4p[2 * t]; v = r4p[2 * t + 1];
        s0 += u.x * u.x; s1 += u.y * u.y; s2 += u.z * u.z; s3 += u.w * u.w;
        s4 += v.x * v.x; s5 += v.y * v.y; s6 += v.z * v.z; s7 += v.w * v.w;
      }
      A = ((s0 + s1) + (s2 + s3)) + ((s4 + s5) + (s6 + s7));
    }
    const float* cbk = cb + ((size_t)k << 17);
    const float* nk = norms + (k << 10);
    float bestE = 3.4e38f;
    int bestI = c0;
    for (int blk = 0; blk < 16; ++blk) {              // 8 codes per block
      const int cbase = c0 + (blk << 3);
      const float* cp = cbk + ((size_t)cbase << 7);   // wave-uniform address
      float E0 = 0.f, E1 = 0.f, E2 = 0.f, E3 = 0.f;
      float E4 = 0.f, E5 = 0.f, E6 = 0.f, E7 = 0.f;
      for (int kk = 0; kk < 32; ++kk) {               // k4 chunks, ascending
        float4 r4 = r4p[kk];                          // own row from LDS
        const float4* c4 = (const float4*)(cp + (kk << 2));
        float4 q0 = c4[0];                            // code j at +j*32 float4s
        float4 q1 = c4[32];
        float4 q2 = c4[64];
        float4 q3 = c4[96];
        float4 q4 = c4[128];
        float4 q5 = c4[160];
        float4 q6 = c4[192];
        float4 q7 = c4[224];
        E0 = fmaf(r4.x, q0.x, E0); E0 = fmaf(r4.y, q0.y, E0);
        E0 = fmaf(r4.z, q0.z, E0); E0 = fmaf(r4.w, q0.w, E0);
        E1 = fmaf(r4.x, q1.x, E1); E1 = fmaf(r4.y, q1.y, E1);
        E1 = fmaf(r4.z, q1.z, E1); E1 = fmaf(r4.w, q1.w, E1);
        E2 = fmaf(r4.x, q2.x, E2); E2 = fmaf(r4.y, q2.y, E2);
        E2 = fmaf(r4.z, q2.z, E2); E2 = fmaf(r4.w, q2.w, E2);
        E3 = fmaf(r4.x, q3.x, E3); E3 = fmaf(r4.y, q3.y, E3);
        E3 = fmaf(r4.z, q3.z, E3); E3 = fmaf(r4.w, q3.w, E3);
        E4 = fmaf(r4.x, q4.x, E4); E4 = fmaf(r4.y, q4.y, E4);
        E4 = fmaf(r4.z, q4.z, E4); E4 = fmaf(r4.w, q4.w, E4);
        E5 = fmaf(r4.x, q5.x, E5); E5 = fmaf(r4.y, q5.y, E5);
        E5 = fmaf(r4.z, q5.z, E5); E5 = fmaf(r4.w, q5.w, E5);
        E6 = fmaf(r4.x, q6.x, E6); E6 = fmaf(r4.y, q6.y, E6);
        E6 = fmaf(r4.z, q6.z, E6); E6 = fmaf(r4.w, q6.w, E6);
        E7 = fmaf(r4.x, q7.x, E7); E7 = fmaf(r4.y, q7.y, E7);
        E7 = fmaf(r4.z, q7.z, E7); E7 = fmaf(r4.w, q7.w, E7);
      }
      {                                               // exact e, np_d2_blas form
#pragma clang fp contract(off)
        float e;
        e = (A - 2.0f * E0) + nk[cbase + 0];
        if (e < bestE) { bestE = e; bestI = cbase + 0; }
        e = (A - 2.0f * E1) + nk[cbase + 1];
        if (e < bestE) { bestE = e; bestI = cbase + 1; }
        e = (A - 2.0f * E2) + nk[cbase + 2];
        if (e < bestE) { bestE = e; bestI = cbase + 2; }
        e = (A - 2.0f * E3) + nk[cbase + 3];
        if (e < bestE) { bestE = e; bestI = cbase + 3; }
        e = (A - 2.0f * E4) + nk[cbase + 4];
        if (e < bestE) { bestE = e; bestI = cbase + 4; }
        e = (A - 2.0f * E5) + nk[cbase + 5];
        if (e < bestE) { bestE = e; bestI = cbase + 5; }
        e = (A - 2.0f * E6) + nk[cbase + 6];
        if (e < bestE) { bestE = e; bestI = cbase + 6; }
        e = (A - 2.0f * E7) + nk[cbase + 7];
        if (e < bestE) { bestE = e; bestI = cbase + 7; }
      }
    }
    candV[wave][lane] = bestE;
    candI[wave][lane] = bestI;
    __syncthreads();
    if (wave == 0) {                                  // merge, ascending waves
      float mv = candV[0][lane];
      int mi = candI[0][lane];
#pragma unroll
      for (int w = 1; w < 8; ++w) {
        float v = candV[w][lane];
        int ci = candI[w][lane];
        if (v < mv || (v == mv && ci < mi)) { mv = v; mi = ci; }
      }
      chosen[lane] = mi;
      outIdx[(k << 15) + row] = (float)mi;
    }
    __syncthreads();
    {                                                 // subtract, exact single sub
      const int r0 = tid & 63, seg = tid >> 6;
      const float* q = cbk + ((size_t)chosen[r0] << 7) + seg * 16;
      float* rp = rS + r0 * RSTRIDE + seg * 16;
#pragma unroll
      for (int d = 0; d < 16; ++d) rp[d] = rp[d] - q[d];
    }
    __syncthreads();
  }
}

// ---- E: quantized (fp32 k-order accumulate + STE) + closs partials -----------
__global__ __launch_bounds__(256) void quant_closs(const float* __restrict__ cb,
                                                   const float* __restrict__ x,
                                                   const float* __restrict__ idxF,
                                                   float* __restrict__ outQ,
                                                   double* __restrict__ partials) {
  int gid = blockIdx.x * 256 + threadIdx.x;          // 0..131071
  int row = gid >> 2;
  int d0 = (gid & 3) << 5;
  const float* xr = x + (size_t)row * 128 + d0;
  float xv[32], qv[32];
#pragma unroll
  for (int i = 0; i < 32; ++i) { xv[i] = xr[i]; qv[i] = 0.f; }
  double cl = 0.0;
  for (int k = 0; k < 32; ++k) {
    int c = (int)idxF[(k << 15) + row];
    const float* qp = cb + ((size_t)k << 17) + ((size_t)c << 7) + d0;
#pragma unroll
    for (int i = 0; i < 32; ++i) {
      float v = qp[i];
      qv[i] = qv[i] + v;                  // fp32 adds in k-order (np order)
      float e = v - xv[i];
      cl += (double)e * (double)e;
    }
  }
  float* op = outQ + (size_t)row * 128 + d0;
#pragma unroll
  for (int i = 0; i < 32; ++i) op[i] = np_ste(xv[i], qv[i]);
  __shared__ double red[256];
  red[threadIdx.x] = cl;
  __syncthreads();
  for (int s = 128; s > 0; s >>= 1) {
    if (threadIdx.x < s) red[threadIdx.x] += red[threadIdx.x + s];
    __syncthreads();
  }
  if (threadIdx.x == 0) partials[blockIdx.x] = red[0];
}

// ---- F: final closs reduction ------------------------------------------------
__global__ __launch_bounds__(256) void closs_final(const double* __restrict__ partials,
                                                   float* __restrict__ out) {
  __shared__ double red[256];
  red[threadIdx.x] = partials[threadIdx.x] + partials[threadIdx.x + 256];
  __syncthreads();
  for (int s = 128; s > 0; s >>= 1) {
    if (threadIdx.x < s) red[threadIdx.x] += red[threadIdx.x + s];
    __syncthreads();
  }
  if (threadIdx.x == 0) out[0] = (float)(red[0] * (0.25 / 4194304.0));
}

extern "C" void kernel_launch(void* const* d_in, const int* in_sizes, int n_in,
                              void* d_out, int out_size, void* d_ws, size_t ws_size,
                              hipStream_t stream) {
  const float* af    = (const float*)d_in[0];
  const float* ctx   = (const float*)d_in[1];
  const float* in_w  = (const float*)d_in[2];
  const float* in_b  = (const float*)d_in[3];
  const float* cb    = (const float*)d_in[4];
  const float* sem_w = (const float*)d_in[5];
  const float* sem_b = (const float*)d_in[6];

  float* out     = (float*)d_out;
  float* outQ    = out;
  float* outIdx  = out + 4194304;
  float* outLoss = out + 5242880;

  float*  ws_bias  = (float*)d_ws;                    // 10240
  float*  ws_x     = ws_bias + 10240;                 // 4194304
  float*  ws_norms = ws_x + 4194304;                  // 32768
  double* ws_part  = (double*)(ws_norms + 32768);     // 512 doubles

  hipLaunchKernelGGL(code_norms_np, dim3(128), dim3(256), 0, stream, cb, ws_norms);
  hipLaunchKernelGGL(xproj_blas, dim3(128), dim3(256), 0, stream, af, in_w, in_b, ws_x);
  hipLaunchKernelGGL(sembias_blas, dim3(5), dim3(256), 0, stream, sem_w, sem_b, ctx,
                     ws_bias);
  hipLaunchKernelGGL(rvq_main, dim3(512), dim3(512), 0, stream, cb, ws_norms,
                     ws_bias, ws_x, outIdx);
  hipLaunchKernelGGL(quant_closs, dim3(512), dim3(256), 0, stream, cb, ws_x,
                     outIdx, outQ, ws_part);
  hipLaunchKernelGGL(closs_final, dim3(1), dim3(256), 0, stream, ws_part, outLoss);
}